// Round 17
// baseline (1300.137 us; speedup 1.0000x reference)
//
#include <hip/hip_runtime.h>
#include <hip/hip_bf16.h>

typedef __hip_bfloat16 bf16;
typedef __attribute__((ext_vector_type(8))) short s16x8;   // 8 bf16 (4 VGPR) MFMA A/B frag
typedef __attribute__((ext_vector_type(4))) float f32x4;   // MFMA C/D frag

__device__ __forceinline__ float b2f(bf16 x) { return __bfloat162float(x); }
__device__ __forceinline__ bf16 f2b(float x) { return __float2bfloat16(x); }

__device__ __forceinline__ void gld16(const void* g, void* l) {
  __builtin_amdgcn_global_load_lds((const __attribute__((address_space(1))) unsigned int*)g,
                                   (__attribute__((address_space(3))) unsigned int*)l,
                                   16, 0, 0);
}

#define BARRIER() do { asm volatile("" ::: "memory"); \
                       __builtin_amdgcn_s_barrier();  \
                       asm volatile("" ::: "memory"); } while (0)

// ---------------------------------------------------------------------------
__global__ __launch_bounds__(256) void fill_sentinel(float* out, int n) {
  int idx = blockIdx.x * 256 + threadIdx.x;
  if (idx < n) out[idx] = 100.0f;
}

__global__ __launch_bounds__(256) void zero_fill(bf16* z) {
  z[blockIdx.x * 256 + threadIdx.x] = f2b(0.f);
}

// ---------------------------------------------------------------------------
// pack conv weights (f32 -> bf16): wpN[s][o][c]; wnp[p][t][ot][c][m]
__global__ __launch_bounds__(256) void pack_w(const float* __restrict__ c0w,
                                              const float* __restrict__ c1w,
                                              const float* __restrict__ lw,
                                              bf16* wp0, bf16* wp1, bf16* wp2, bf16* wnp) {
  const int SEG = 9 * 256 * 256;
  int idx = blockIdx.x * 256 + threadIdx.x;
  if (idx < 3 * SEG) {
    int which = idx / SEG, r = idx % SEG;
    int s = r >> 16, o = (r >> 8) & 255, c = r & 255;
    int ky = s / 3, kx = s - 3 * ky;
    if (which == 0)      wp0[r] = f2b(c0w[(((size_t)o * 768 + 256 + c) * 3 + ky) * 3 + kx]);
    else if (which == 1) wp1[r] = f2b(c1w[(((size_t)o * 256 + c) * 3 + ky) * 3 + kx]);
    else                 wp2[r] = f2b(lw [(((size_t)o * 256 + c) * 3 + ky) * 3 + kx]);
  } else {
    int r = idx - 3 * SEG;             // [p][t][ot][c][m]
    int m = r & 255, c = (r >> 8) & 255, tt = r >> 16;
    int ot = tt % 3, t2 = (tt / 3) % 3, p = tt / 9;
    int ky, kx, cin;
    if (p == 0) { kx = t2; ky = ot; cin = c; }        // node_i block
    else        { ky = t2; kx = ot; cin = 512 + c; }  // node_j block
    wnp[r] = f2b(c0w[(((size_t)m * 768 + cin) * 3 + ky) * 3 + kx]);
  }
}

// ---------------------------------------------------------------------------
// adapter 1x1 (one batch): E[i][j][m] = sum_c aw[m][c]*e[i][j][c] + ab[m]
__global__ __launch_bounds__(256) void adapter_k(const float* __restrict__ e,
                                                 const float* __restrict__ aw,
                                                 const float* __restrict__ ab,
                                                 bf16* __restrict__ E) {
  int i = blockIdx.x;
  int m = threadIdx.x;
  __shared__ float se[256 * 7];
  const size_t rb = (size_t)i * (256 * 7);
  for (int idx = m; idx < 256 * 7; idx += 256) se[idx] = e[rb + idx];
  __syncthreads();
  float w[7];
#pragma unroll
  for (int c = 0; c < 7; ++c) w[c] = aw[m * 7 + c];
  float bias = ab[m];
  bf16* ob = E + (size_t)i * 65536 + m;
  for (int j = 0; j < 256; ++j) {
    const float* ej = se + j * 7;
    float a = bias;
#pragma unroll
    for (int c = 0; c < 7; ++c) a += w[c] * ej[c];
    ob[(size_t)j * 256] = f2b(a);
  }
}

// ---------------------------------------------------------------------------
// node terms: TT[p*3+t][pos][m]; grid = p(2) x t(3) x chunk(64 of 4 positions)
template <typename T>
__global__ __launch_bounds__(256) void node_terms(const T* __restrict__ nd,
                                                  const bf16* __restrict__ wnp,
                                                  float* __restrict__ TT) {
  int bid = blockIdx.x;
  int chunk = bid & 63;
  int t = (bid >> 6) % 3;
  int p = bid / 192;
  int tid = threadIdx.x;
  __shared__ float snd[6][256];
  int pos0 = chunk * 4;
  for (int idx = tid; idx < 6 * 256; idx += 256) {
    int r = idx >> 8, c = idx & 255;
    int gp = pos0 - 1 + r;
    snd[r][c] = (gp >= 0 && gp < 256) ? (float)nd[(size_t)gp * 256 + c] : 0.f;
  }
  __syncthreads();
  float acc[4] = {0.f, 0.f, 0.f, 0.f};
  const bf16* wb = wnp + (size_t)((p * 3 + t) * 3) * 65536 + tid;
  for (int c = 0; c < 256; ++c) {
    float w0 = b2f(wb[(size_t)c * 256]);
    float w1 = b2f(wb[(size_t)(65536 + c * 256)]);
    float w2 = b2f(wb[(size_t)(2 * 65536 + c * 256)]);
#pragma unroll
    for (int ii = 0; ii < 4; ++ii)
      acc[ii] += w0 * snd[ii][c] + w1 * snd[ii + 1][c] + w2 * snd[ii + 2][c];
  }
  float* o = TT + (((size_t)(p * 3 + t) * 256 + pos0) * 256) + tid;
#pragma unroll
  for (int ii = 0; ii < 4; ++ii) o[(size_t)ii * 256] = acc[ii];
}

// ---------------------------------------------------------------------------
// r17: OC-SPLIT -- 2 independent blocks/CU (barrier decoupling).
// Grid 512: block = 256px x 128oc (oh = parity), 256 thr / 4 waves
// (wave = 128px x 64oc, identical frag/acc structure to r16). LDS 64KB/block:
// IN 32KB single-buffer (reg-staged) + W 2x16KB double-buffer (gld DMA)
// -> 2 blocks/CU. Rationale: r5..r16 exonerated schedule/sync/latency/
// staging/addressing via 8 NULLs; the never-varied axis with good-reuse
// tiling is independent workgroups per CU -- at 1 block/CU, every barrier
// idles the whole CU (all waves in one barrier group). Per-CU MFMA and
// LDS-read totals unchanged; input fetch duplicates (L2-hot, 16% HBM).
// Ledger: IN reads < bar#1 < IN writes < bar#2 < next reads; W par p^1 DMA
// issued after bar#2(t-1) (last read of that par was before bar#1(t-1)),
// committed by the vmcnt(0) preceding bar#2(t).
template <int EPI, int F32OUT>
__global__ __launch_bounds__(256, 2)
void conv3x3_k(const bf16* __restrict__ inb, const bf16* __restrict__ wpack,
               const float* __restrict__ bias, void* __restrict__ outv,
               const float* __restrict__ TT, const bf16* __restrict__ zrow) {
  __shared__ __align__(16) char lds[65536];   // [IN 32K | W par0 16K | W par1 16K]
  const int bid = blockIdx.x;                 // 512 = xcd(8) x (i32 x oh2)
  const int rest = bid >> 3;
  const int i = ((bid & 7) << 5) + (rest >> 1);
  const int oh = rest & 1;
  const int tid = threadIdx.x;
  const int lane = tid & 63, wid = tid >> 6;
  const int wr = wid >> 1, wc = wid & 1;      // 2M x 2N wave grid
  const int lo = lane & 15, hi = lane >> 4;
  const int xlane = tid >> 3;                 // [0,32): staging row in 32-row round
  const int sw = ((tid & 7) ^ (xlane & 7)) << 3;  // source granule swizzle (elems)
  const int g16 = (tid & 7) << 4;             // LDS granule byte slot

  // precomputed ds_read lane addresses
  const int gxk0 = (hi ^ (lo & 7)) << 4;
  const int gxk1 = ((4 + hi) ^ (lo & 7)) << 4;
  const int aJ0 = (wr * 128 + lo) * 128 + gxk0;   // + mh*8192 + mf*2048
  const int aJ1 = (wr * 128 + lo) * 128 + gxk1;
  const int bJ0 = 32768 + (wc * 64 + lo) * 128 + gxk0;  // + par*16384 + nh*4096 + nf*2048
  const int bJ1 = 32768 + (wc * 64 + lo) * 128 + gxk1;

  f32x4 acc00[4][2], acc01[4][2], acc10[4][2], acc11[4][2];
  const f32x4 z = {0.f, 0.f, 0.f, 0.f};
#pragma unroll
  for (int mf = 0; mf < 4; ++mf)
#pragma unroll
    for (int nf = 0; nf < 2; ++nf) { acc00[mf][nf] = z; acc01[mf][nf] = z;
                                     acc10[mf][nf] = z; acc11[mf][nf] = z; }
  s16x8 afA[4][2], bf0[2][2], bf1[2][2];
  s16x8 gi[8];                                // IN staged in regs (static idx)

  const bf16* rows0 = (i >= 1)   ? inb + (size_t)(i - 1) * 65536 : zrow;
  const bf16* rows1 = inb + (size_t)i * 65536;
  const bf16* rows2 = (i <= 254) ? inb + (size_t)(i + 1) * 65536 : zrow;

  auto ISSUE_IN = [&](int t) {                // 8 global_load_dwordx4 -> regs
    const int ky = (t >= 24) ? 2 : ((t >= 12) ? 1 : 0);
    const int rem = t - ky * 12;
    const int kx = rem >> 2, cc = rem & 3;
    const bf16* rowp = (ky == 0) ? rows0 : (ky == 1 ? rows1 : rows2);
#pragma unroll
    for (int r = 0; r < 8; ++r) {
      const int px = r * 32 + xlane;
      const int j = px + kx - 1;
      const bf16* src = (j >= 0 && j <= 255)
          ? rowp + ((size_t)j << 8) + cc * 64 + sw
          : zrow + sw;
      gi[r] = *(const s16x8*)src;
    }
  };
  auto GLD_W = [&](int t, int par) {          // 4 gld16 -> W par buffer (DMA)
    const int ky = (t >= 24) ? 2 : ((t >= 12) ? 1 : 0);
    const int rem = t - ky * 12;
    const int kx = rem >> 2, cc = rem & 3;
    const int s = ky * 3 + kx;
#pragma unroll
    for (int r = 0; r < 4; ++r) {
      const int oc = r * 32 + xlane;          // [0,128)
      gld16(wpack + ((size_t)s << 16) + (((size_t)(oh * 128 + oc)) << 8) + cc * 64 + sw,
            lds + 32768 + par * 16384 + ((r * 32 + wid * 8) << 7));
    }
  };
  auto WRITE_IN = [&]() {                     // 8 ds_write_b128
#pragma unroll
    for (int r = 0; r < 8; ++r) {
      const int px = r * 32 + xlane;
      *(s16x8*)(lds + px * 128 + g16) = gi[r];
    }
  };
  auto LD_A = [&](int mh) {
#pragma unroll
    for (int mf = 0; mf < 4; ++mf) {
      afA[mf][0] = *(const s16x8*)(lds + aJ0 + mf * 2048 + mh * 8192);
      afA[mf][1] = *(const s16x8*)(lds + aJ1 + mf * 2048 + mh * 8192);
    }
  };
  auto LD_B = [&](int par, int nh, s16x8 (&dst)[2][2]) {
#pragma unroll
    for (int nf = 0; nf < 2; ++nf) {
      dst[nf][0] = *(const s16x8*)(lds + bJ0 + par * 16384 + nh * 4096 + nf * 2048);
      dst[nf][1] = *(const s16x8*)(lds + bJ1 + par * 16384 + nh * 4096 + nf * 2048);
    }
  };

#define MMA_Q(ACC, BFR)                                                       \
  __builtin_amdgcn_s_setprio(1);                                              \
  _Pragma("unroll") for (int kk = 0; kk < 2; ++kk)                            \
  _Pragma("unroll") for (int mf = 0; mf < 4; ++mf)                            \
  _Pragma("unroll") for (int nf = 0; nf < 2; ++nf)                            \
    ACC[mf][nf] = __builtin_amdgcn_mfma_f32_16x16x32_bf16(                    \
        afA[mf][kk], BFR[nf][kk], ACC[mf][nf], 0, 0, 0);                      \
  __builtin_amdgcn_s_setprio(0);

  // prologue: stage tile 0 (W -> par0 via DMA, IN -> regs -> LDS)
  GLD_W(0, 0);
  ISSUE_IN(0);
  asm volatile("s_waitcnt vmcnt(0)" ::: "memory");
  WRITE_IN();
  asm volatile("s_waitcnt lgkmcnt(0)" ::: "memory");
  BARRIER();

#pragma unroll 1
  for (int t = 0; t < 36; ++t) {
    const int p = t & 1;
    if (t < 35) { GLD_W(t + 1, p ^ 1); ISSUE_IN(t + 1); }
    LD_A(0); LD_B(p, 0, bf0); LD_B(p, 1, bf1);
    MMA_Q(acc00, bf0);
    MMA_Q(acc01, bf1);
    LD_A(1);
    MMA_Q(acc10, bf0);
    MMA_Q(acc11, bf1);
    BARRIER();                                // #1: all reads of IN + W(par p) done
    if (t < 35) {
      asm volatile("s_waitcnt vmcnt(0)" ::: "memory");  // gi arrived; W DMA committed
      WRITE_IN();
    }
    asm volatile("s_waitcnt lgkmcnt(0)" ::: "memory");
    BARRIER();                                // #2: IN(t+1) visible to all waves
  }
#undef MMA_Q

  // epilogue: px j = wr*128 + MH*64 + mf*16 + hi*4 + rr; oc o = oh*128 + ...
  bf16* orow = (bf16*)outv + (size_t)i * 65536;
  float* orowf = (float*)outv + (size_t)i * 65536;
#define EPI_Q(ACC, MH, NH)                                                    \
  _Pragma("unroll") for (int mf = 0; mf < 4; ++mf) {                          \
    _Pragma("unroll") for (int nf = 0; nf < 2; ++nf) {                        \
      const int o = oh * 128 + wc * 64 + NH * 32 + nf * 16 + lo;              \
      const float bs = bias[o];                                               \
      float ni0 = 0.f, ni1 = 0.f, ni2 = 0.f;                                  \
      if (EPI) { const float* TI = TT + (size_t)i * 256 + o;                  \
        ni0 = TI[0]; ni1 = TI[65536]; ni2 = TI[2 * 65536]; }                  \
      _Pragma("unroll") for (int rr = 0; rr < 4; ++rr) {                      \
        const int j = wr * 128 + MH * 64 + mf * 16 + hi * 4 + rr;             \
        float v = ACC[mf][nf][rr] + bs;                                       \
        if (EPI) {                                                            \
          v += ni1 + (j > 0 ? ni0 : 0.f) + (j < 255 ? ni2 : 0.f);             \
          const float* TJ = TT + (size_t)3 * 65536 + (size_t)j * 256 + o;     \
          float nj0 = TJ[0], nj1 = TJ[65536], nj2 = TJ[2 * 65536];            \
          v += nj1 + (i > 0 ? nj0 : 0.f) + (i < 255 ? nj2 : 0.f); }           \
        v = fmaxf(v, 0.f);                                                    \
        if (F32OUT) orowf[(size_t)j * 256 + o] = v;                           \
        else        orow[(size_t)j * 256 + o] = f2b(v);                       \
      } } }
  EPI_Q(acc00, 0, 0); EPI_Q(acc01, 0, 1); EPI_Q(acc10, 1, 0); EPI_Q(acc11, 1, 1);
#undef EPI_Q
}

// ---------------------------------------------------------------------------
// fused: att = leaky(1x1(feat)); coeff = softmax_j; nd[i][m] = sum_j coeff*feat
template <int F32OUT>
__global__ __launch_bounds__(256) void att_wsum(const bf16* __restrict__ feat,
                                                const float* __restrict__ aw,
                                                const float* __restrict__ ab,
                                                bf16* __restrict__ ndb,
                                                float* __restrict__ ndf) {
  int i = blockIdx.x;
  int tid = threadIdx.x, lane = tid & 63, w = tid >> 6;
  __shared__ float s_aw[256];
  __shared__ float s_att[256];
  __shared__ float s_red[8];
  s_aw[tid] = aw[tid];
  __syncthreads();
  float a0 = s_aw[lane * 4], a1 = s_aw[lane * 4 + 1];
  float a2 = s_aw[lane * 4 + 2], a3 = s_aw[lane * 4 + 3];
  const bf16* fb = feat + (size_t)i * 65536;
  float abv = ab[0];
  for (int jj = 0; jj < 64; ++jj) {
    int j = w * 64 + jj;
    const bf16* f = fb + (size_t)j * 256 + lane * 4;
    float v = a0 * b2f(f[0]) + a1 * b2f(f[1]) + a2 * b2f(f[2]) + a3 * b2f(f[3]);
#pragma unroll
    for (int mk = 32; mk; mk >>= 1) v += __shfl_xor(v, mk);
    if (lane == 0) { float a = v + abv; s_att[j] = a > 0.f ? a : 0.01f * a; }
  }
  __syncthreads();
  float x = s_att[tid];
  float mx = x;
#pragma unroll
  for (int mk = 32; mk; mk >>= 1) mx = fmaxf(mx, __shfl_xor(mx, mk));
  if (lane == 0) s_red[w] = mx;
  __syncthreads();
  mx = fmaxf(fmaxf(s_red[0], s_red[1]), fmaxf(s_red[2], s_red[3]));
  float e = expf(x - mx);
  float sm = e;
#pragma unroll
  for (int mk = 32; mk; mk >>= 1) sm += __shfl_xor(sm, mk);
  if (lane == 0) s_red[4 + w] = sm;
  __syncthreads();
  sm = s_red[4] + s_red[5] + s_red[6] + s_red[7];
  __syncthreads();
  s_att[tid] = e / sm;
  __syncthreads();
  float acc = 0.f;
  for (int j = 0; j < 256; ++j) acc += s_att[j] * b2f(fb[(size_t)j * 256 + tid]);
  if (F32OUT) ndf[(size_t)i * 256 + tid] = acc;
  else        ndb[(size_t)i * 256 + tid] = f2b(acc);
}

// ---------------------------------------------------------------------------
extern "C" void kernel_launch(void* const* d_in, const int* in_sizes, int n_in,
                              void* d_out, int out_size, void* d_ws, size_t ws_size,
                              hipStream_t stream) {
  const float* edge_feats = (const float*)d_in[0];
  const float* node_feats = (const float*)d_in[1];
  const float* adapter_w  = (const float*)d_in[2];
  const float* adapter_b  = (const float*)d_in[3];
  const float* conv0_w    = (const float*)d_in[4];
  const float* conv0_b    = (const float*)d_in[5];
  const float* conv1_w    = (const float*)d_in[6];
  const float* conv1_b    = (const float*)d_in[7];
  const float* last_w     = (const float*)d_in[8];
  const float* last_b     = (const float*)d_in[9];
  const float* att_w      = (const float*)d_in[10];
  const float* att_b      = (const float*)d_in[11];
  float* out = (float*)d_out;

  char* ws = (char*)d_ws;
  size_t off = 0;
  bf16* Q    = (bf16*)(ws + off); off += (size_t)256 * 256 * 256 * 2;     // 33,554,432
  bf16* WP0  = (bf16*)(ws + off); off += (size_t)9 * 65536 * 2;
  bf16* WP1  = (bf16*)(ws + off); off += (size_t)9 * 65536 * 2;
  bf16* WP2  = (bf16*)(ws + off); off += (size_t)9 * 65536 * 2;
  bf16* WNP  = (bf16*)(ws + off); off += (size_t)18 * 65536 * 2;          //  2,359,296
  float* TT  = (float*)(ws + off); off += (size_t)2 * 3 * 65536 * 4;      //  1,572,864
  bf16* ND   = (bf16*)(ws + off); off += (size_t)65536 * 2;               //    131,072
  bf16* ZROW = (bf16*)(ws + off); off += (size_t)65536 * 2;               //    131,072 zeros
  if (ws_size < off) {   // ~41.3 MB (proven available)
    fill_sentinel<<<(out_size + 255) / 256, 256, 0, stream>>>(out, out_size);
    return;
  }

  zero_fill<<<256, 256, 0, stream>>>(ZROW);
  pack_w<<<11520, 256, 0, stream>>>(conv0_w, conv1_w, last_w, WP0, WP1, WP2, WNP);

  for (int b = 0; b < 2; ++b) {
    // P: bf16 scratch inside the (f32) edge-out region of batch b
    bf16* P = (bf16*)(out + 131072 + (size_t)b * 16777216);
    float* edge_out = out + 131072 + (size_t)b * 16777216;
    float* node_out = out + (size_t)b * 65536;
    const float* eb = edge_feats + (size_t)b * 458752;
    const float* nb = node_feats + (size_t)b * 65536;

    adapter_k<<<256, 256, 0, stream>>>(eb, adapter_w, adapter_b, P);                   // E  @ P
    // block 1
    node_terms<float><<<384, 256, 0, stream>>>(nb, WNP, TT);
    conv3x3_k<1, 0><<<512, 256, 0, stream>>>(P, WP0, conv0_b, Q, TT, ZROW);            // A  @ Q
    conv3x3_k<0, 0><<<512, 256, 0, stream>>>(Q, WP1, conv1_b, P, nullptr, ZROW);       // B  @ P
    att_wsum<0><<<256, 256, 0, stream>>>(P, att_w, att_b, ND, nullptr);                // nd1 @ ND
    conv3x3_k<0, 0><<<512, 256, 0, stream>>>(P, WP2, last_b, Q, nullptr, ZROW);        // C  @ Q
    // block 2
    node_terms<bf16><<<384, 256, 0, stream>>>(ND, WNP, TT);
    conv3x3_k<1, 0><<<512, 256, 0, stream>>>(Q, WP0, conv0_b, P, TT, ZROW);            // D  @ P
    conv3x3_k<0, 0><<<512, 256, 0, stream>>>(P, WP1, conv1_b, Q, nullptr, ZROW);       // E2 @ Q
    att_wsum<1><<<256, 256, 0, stream>>>(Q, att_w, att_b, nullptr, node_out);          // node out (f32)
    conv3x3_k<0, 1><<<512, 256, 0, stream>>>(Q, WP2, last_b, edge_out, nullptr, ZROW); // edge out (f32)
  }
}

// Round 18
// 1194.331 us; speedup vs baseline: 1.0886x; 1.0886x over previous
//
#include <hip/hip_runtime.h>
#include <hip/hip_bf16.h>

typedef __hip_bfloat16 bf16;
typedef __attribute__((ext_vector_type(8))) short s16x8;   // 8 bf16 (4 VGPR) MFMA A/B frag
typedef __attribute__((ext_vector_type(4))) float f32x4;   // MFMA C/D frag

__device__ __forceinline__ float b2f(bf16 x) { return __bfloat162float(x); }
__device__ __forceinline__ bf16 f2b(float x) { return __float2bfloat16(x); }

__device__ __forceinline__ void gld16(const void* g, void* l) {
  __builtin_amdgcn_global_load_lds((const __attribute__((address_space(1))) unsigned int*)g,
                                   (__attribute__((address_space(3))) unsigned int*)l,
                                   16, 0, 0);
}

#define BARRIER() do { asm volatile("" ::: "memory"); \
                       __builtin_amdgcn_s_barrier();  \
                       asm volatile("" ::: "memory"); } while (0)

// ---------------------------------------------------------------------------
__global__ __launch_bounds__(256) void fill_sentinel(float* out, int n) {
  int idx = blockIdx.x * 256 + threadIdx.x;
  if (idx < n) out[idx] = 100.0f;
}

__global__ __launch_bounds__(64) void zero_zb(bf16* zb) {
  zb[threadIdx.x * 2] = f2b(0.f);
  zb[threadIdx.x * 2 + 1] = f2b(0.f);
}

// ---------------------------------------------------------------------------
// pack conv weights (f32 -> bf16): wpN[s][o][c]; wnp[p][t][ot][c][m]
__global__ __launch_bounds__(256) void pack_w(const float* __restrict__ c0w,
                                              const float* __restrict__ c1w,
                                              const float* __restrict__ lw,
                                              bf16* wp0, bf16* wp1, bf16* wp2, bf16* wnp) {
  const int SEG = 9 * 256 * 256;
  int idx = blockIdx.x * 256 + threadIdx.x;
  if (idx < 3 * SEG) {
    int which = idx / SEG, r = idx % SEG;
    int s = r >> 16, o = (r >> 8) & 255, c = r & 255;
    int ky = s / 3, kx = s - 3 * ky;
    if (which == 0)      wp0[r] = f2b(c0w[(((size_t)o * 768 + 256 + c) * 3 + ky) * 3 + kx]);
    else if (which == 1) wp1[r] = f2b(c1w[(((size_t)o * 256 + c) * 3 + ky) * 3 + kx]);
    else                 wp2[r] = f2b(lw [(((size_t)o * 256 + c) * 3 + ky) * 3 + kx]);
  } else {
    int r = idx - 3 * SEG;             // [p][t][ot][c][m]
    int m = r & 255, c = (r >> 8) & 255, tt = r >> 16;
    int ot = tt % 3, t2 = (tt / 3) % 3, p = tt / 9;
    int ky, kx, cin;
    if (p == 0) { kx = t2; ky = ot; cin = c; }        // node_i block
    else        { ky = t2; kx = ot; cin = 512 + c; }  // node_j block
    wnp[r] = f2b(c0w[(((size_t)m * 768 + cin) * 3 + ky) * 3 + kx]);
  }
}

// ---------------------------------------------------------------------------
// adapter 1x1 (one batch): E[i][j][m] = sum_c aw[m][c]*e[i][j][c] + ab[m]
__global__ __launch_bounds__(256) void adapter_k(const float* __restrict__ e,
                                                 const float* __restrict__ aw,
                                                 const float* __restrict__ ab,
                                                 bf16* __restrict__ E) {
  int i = blockIdx.x;
  int m = threadIdx.x;
  __shared__ float se[256 * 7];
  const size_t rb = (size_t)i * (256 * 7);
  for (int idx = m; idx < 256 * 7; idx += 256) se[idx] = e[rb + idx];
  __syncthreads();
  float w[7];
#pragma unroll
  for (int c = 0; c < 7; ++c) w[c] = aw[m * 7 + c];
  float bias = ab[m];
  bf16* ob = E + (size_t)i * 65536 + m;
  for (int j = 0; j < 256; ++j) {
    const float* ej = se + j * 7;
    float a = bias;
#pragma unroll
    for (int c = 0; c < 7; ++c) a += w[c] * ej[c];
    ob[(size_t)j * 256] = f2b(a);
  }
}

// ---------------------------------------------------------------------------
// node terms: TT[p*3+t][pos][m]; grid = p(2) x t(3) x chunk(64 of 4 positions)
template <typename T>
__global__ __launch_bounds__(256) void node_terms(const T* __restrict__ nd,
                                                  const bf16* __restrict__ wnp,
                                                  float* __restrict__ TT) {
  int bid = blockIdx.x;
  int chunk = bid & 63;
  int t = (bid >> 6) % 3;
  int p = bid / 192;
  int tid = threadIdx.x;
  __shared__ float snd[6][256];
  int pos0 = chunk * 4;
  for (int idx = tid; idx < 6 * 256; idx += 256) {
    int r = idx >> 8, c = idx & 255;
    int gp = pos0 - 1 + r;
    snd[r][c] = (gp >= 0 && gp < 256) ? (float)nd[(size_t)gp * 256 + c] : 0.f;
  }
  __syncthreads();
  float acc[4] = {0.f, 0.f, 0.f, 0.f};
  const bf16* wb = wnp + (size_t)((p * 3 + t) * 3) * 65536 + tid;
  for (int c = 0; c < 256; ++c) {
    float w0 = b2f(wb[(size_t)c * 256]);
    float w1 = b2f(wb[(size_t)(65536 + c * 256)]);
    float w2 = b2f(wb[(size_t)(2 * 65536 + c * 256)]);
#pragma unroll
    for (int ii = 0; ii < 4; ++ii)
      acc[ii] += w0 * snd[ii][c] + w1 * snd[ii + 1][c] + w2 * snd[ii + 2][c];
  }
  float* o = TT + (((size_t)(p * 3 + t) * 256 + pos0) * 256) + tid;
#pragma unroll
  for (int ii = 0; ii < 4; ++ii) o[(size_t)ii * 256] = acc[ii];
}

// ---------------------------------------------------------------------------
// 256x256-tile pipelined implicit-GEMM 3x3 conv -- SESSION-BEST (r10, 1193us).
// Deep-slack staging: all 4 W loads at ph1, all 4 IN loads at ph2 (kt+1).
// Ledger per wave (oldest->newest): W0..3,IN0,IN1,IN2,IN3.
//   ph2 gate vmcnt(8): waits IN r2,r3 of kt (issued ~6 phases ago, free);
//   ph4 gate vmcnt(2): waits W0-3 + IN r0,r1 of kt+1 (>=2 phases cover).
// B-fragments bfr0/bfr1 held in registers across phases (24 ds_read/K-tile).
// AF mapping x = mh*128 + wr*64 (phase order == staging order; r8 race fix).
// NOTE (r11-r17 ablations, all NULL): barrier flavor, counted-vs-drain vmcnt,
// phase granularity (1/4/8-phase), address-VALU precompute, reg-staging vs
// gld DMA, 2 blocks/CU oc-split -- per-CU throughput invariant at ~6200
// cyc/512-MFMA K-tile (~35% MfmaUtil). This is the structure's plateau.
template <int EPI, int F32OUT>
__global__ __launch_bounds__(512, 1)
void conv3x3_k(const bf16* __restrict__ inb, const bf16* __restrict__ wpack,
               const float* __restrict__ bias, void* __restrict__ outv,
               const float* __restrict__ TT, const bf16* __restrict__ zbuf) {
  __shared__ __align__(16) char lds[131072];  // 2 x (32KB input | 32KB weights)
  const int bid = blockIdx.x;                 // 256 = xcd(8) x slot(32)
  const int i = ((bid & 7) << 5) + (bid >> 3);  // 32-row band per XCD
  const int tid = threadIdx.x;
  const int lane = tid & 63, wid = tid >> 6;
  const int wr = wid >> 2, wc = wid & 3;      // 2M x 4N wave grid
  const int lo = lane & 15, hi = lane >> 4;
  const int Gs = tid & 7;

  f32x4 acc00[4][2], acc01[4][2], acc10[4][2], acc11[4][2];
  const f32x4 z = {0.f, 0.f, 0.f, 0.f};
#pragma unroll
  for (int mf = 0; mf < 4; ++mf)
#pragma unroll
    for (int nf = 0; nf < 2; ++nf) { acc00[mf][nf] = z; acc01[mf][nf] = z;
                                     acc10[mf][nf] = z; acc11[mf][nf] = z; }
  s16x8 af[4][2], bfr0[2][2], bfr1[2][2];

  // valid ky taps are a contiguous s-range (i=0 drops ky=0, i=255 drops ky=2)
  const int s_lo = (i == 0) ? 3 : 0;
  const int s_hi = (i == 255) ? 5 : 8;
  const int nt = (s_hi - s_lo + 1) * 4;       // K-tiles of 64 ch

  auto STAGE_IN = [&](int t, int r) {         // input round r: px x=r*64+tid/8
    const int s = s_lo + (t >> 2);
    const int ky = s / 3, kx = s - 3 * ky;
    const int cb = (t & 3) * 64;
    const int x = r * 64 + (tid >> 3);
    const int j = x + kx - 1;
    const int sw = (Gs ^ (x & 7)) << 3;
    const bf16* src = (j >= 0 && j <= 255)
        ? inb + (size_t)(i + ky - 1) * 65536 + ((size_t)j << 8) + cb + sw
        : zbuf + sw;
    gld16(src, lds + (t & 1) * 65536 + ((r * 64 + wid * 8) << 7));
  };
  auto STAGE_W = [&](int t, int r) {          // weight round r: oc o=r*64+tid/8
    const int s = s_lo + (t >> 2);
    const int cb = (t & 3) * 64;
    const int o = r * 64 + (tid >> 3);
    gld16(wpack + ((size_t)(s * 256 + o) << 8) + cb + ((Gs ^ (o & 7)) << 3),
          lds + (t & 1) * 65536 + 32768 + ((r * 64 + wid * 8) << 7));
  };
  auto LD_AF = [&](int buf, int mh) {         // reads IN rounds mh*2 + wr
#pragma unroll
    for (int mf = 0; mf < 4; ++mf)
#pragma unroll
      for (int kk = 0; kk < 2; ++kk) {
        const int x = mh * 128 + wr * 64 + mf * 16 + lo;
        af[mf][kk] = *(const s16x8*)(lds + buf * 65536 + x * 128 +
                                     (((kk * 4 + hi) ^ (lo & 7)) << 4));
      }
  };
  auto LD_BF = [&](int buf, int nh, s16x8 (&dst)[2][2]) {  // reads W round wc
#pragma unroll
    for (int nf = 0; nf < 2; ++nf)
#pragma unroll
      for (int kk = 0; kk < 2; ++kk) {
        const int o = wc * 64 + nh * 32 + nf * 16 + lo;
        dst[nf][kk] = *(const s16x8*)(lds + buf * 65536 + 32768 + o * 128 +
                                      (((kk * 4 + hi) ^ (lo & 7)) << 4));
      }
  };

#define MMA_Q(ACC, BFR)                                                       \
  __builtin_amdgcn_s_setprio(1);                                              \
  _Pragma("unroll") for (int mf = 0; mf < 4; ++mf)                            \
  _Pragma("unroll") for (int nf = 0; nf < 2; ++nf)                            \
  _Pragma("unroll") for (int kk = 0; kk < 2; ++kk)                            \
    ACC[mf][nf] = __builtin_amdgcn_mfma_f32_16x16x32_bf16(                    \
        af[mf][kk], BFR[nf][kk], ACC[mf][nf], 0, 0, 0);                       \
  __builtin_amdgcn_s_setprio(0);

  // prologue: stage K-tile 0 in steady-state order (W0..3 then IN0..3),
  // gate vmcnt(2) (leaves IN r2,r3 in flight -> loop invariant)
#pragma unroll
  for (int r = 0; r < 4; ++r) STAGE_W(0, r);
#pragma unroll
  for (int r = 0; r < 4; ++r) STAGE_IN(0, r);
  asm volatile("s_waitcnt vmcnt(2)" ::: "memory");
  BARRIER();

  for (int kt = 0; kt < nt; ++kt) {
    const int buf = kt & 1;
    const bool pf = (kt + 1 < nt);
    // phase 1: (mh0,nh0); issue all W(kt+1)
    LD_AF(buf, 0); LD_BF(buf, 0, bfr0);
    if (pf) { STAGE_W(kt + 1, 0); STAGE_W(kt + 1, 1);
              STAGE_W(kt + 1, 2); STAGE_W(kt + 1, 3); }
    BARRIER();
    MMA_Q(acc00, bfr0);
    // phase 2: (mh0,nh1); issue all IN(kt+1); gate IN r2,r3 of kt (ancient)
    LD_BF(buf, 1, bfr1);
    if (pf) { STAGE_IN(kt + 1, 0); STAGE_IN(kt + 1, 1);
              STAGE_IN(kt + 1, 2); STAGE_IN(kt + 1, 3); }
    if (pf) asm volatile("s_waitcnt vmcnt(8)" ::: "memory");
    else    asm volatile("s_waitcnt vmcnt(0)" ::: "memory");
    BARRIER();
    MMA_Q(acc01, bfr1);
    // phase 3: (mh1,nh0) -- IN r2,r3 guaranteed; bfr0 held in regs
    LD_AF(buf, 1);
    BARRIER();
    MMA_Q(acc10, bfr0);
    // phase 4: (mh1,nh1); gate W0-3 + IN r0,r1 of kt+1 (>=2 phases cover)
    if (pf) asm volatile("s_waitcnt vmcnt(2)" ::: "memory");
    BARRIER();
    MMA_Q(acc11, bfr1);
  }
#undef MMA_Q

  // epilogue: px j = MH*128 + wr*64 + mf*16 + hi*4 + rr
  bf16* orow = (bf16*)outv + (size_t)i * 65536;
  float* orowf = (float*)outv + (size_t)i * 65536;
#define EPI_Q(ACC, MH, NH)                                                    \
  _Pragma("unroll") for (int mf = 0; mf < 4; ++mf) {                          \
    _Pragma("unroll") for (int nf = 0; nf < 2; ++nf) {                        \
      const int o = wc * 64 + NH * 32 + nf * 16 + lo;                         \
      const float bs = bias[o];                                               \
      float ni0 = 0.f, ni1 = 0.f, ni2 = 0.f;                                  \
      if (EPI) { const float* TI = TT + (size_t)i * 256 + o;                  \
        ni0 = TI[0]; ni1 = TI[65536]; ni2 = TI[2 * 65536]; }                  \
      _Pragma("unroll") for (int rr = 0; rr < 4; ++rr) {                      \
        const int j = MH * 128 + wr * 64 + mf * 16 + hi * 4 + rr;             \
        float v = ACC[mf][nf][rr] + bs;                                       \
        if (EPI) {                                                            \
          v += ni1 + (j > 0 ? ni0 : 0.f) + (j < 255 ? ni2 : 0.f);             \
          const float* TJ = TT + (size_t)3 * 65536 + (size_t)j * 256 + o;     \
          float nj0 = TJ[0], nj1 = TJ[65536], nj2 = TJ[2 * 65536];            \
          v += nj1 + (i > 0 ? nj0 : 0.f) + (i < 255 ? nj2 : 0.f); }           \
        v = fmaxf(v, 0.f);                                                    \
        if (F32OUT) orowf[(size_t)j * 256 + o] = v;                           \
        else        orow[(size_t)j * 256 + o] = f2b(v);                       \
      } } }
  EPI_Q(acc00, 0, 0); EPI_Q(acc01, 0, 1); EPI_Q(acc10, 1, 0); EPI_Q(acc11, 1, 1);
#undef EPI_Q
}

// ---------------------------------------------------------------------------
// fused: att = leaky(1x1(feat)); coeff = softmax_j; nd[i][m] = sum_j coeff*feat
template <int F32OUT>
__global__ __launch_bounds__(256) void att_wsum(const bf16* __restrict__ feat,
                                                const float* __restrict__ aw,
                                                const float* __restrict__ ab,
                                                bf16* __restrict__ ndb,
                                                float* __restrict__ ndf) {
  int i = blockIdx.x;
  int tid = threadIdx.x, lane = tid & 63, w = tid >> 6;
  __shared__ float s_aw[256];
  __shared__ float s_att[256];
  __shared__ float s_red[8];
  s_aw[tid] = aw[tid];
  __syncthreads();
  float a0 = s_aw[lane * 4], a1 = s_aw[lane * 4 + 1];
  float a2 = s_aw[lane * 4 + 2], a3 = s_aw[lane * 4 + 3];
  const bf16* fb = feat + (size_t)i * 65536;
  float abv = ab[0];
  for (int jj = 0; jj < 64; ++jj) {
    int j = w * 64 + jj;
    const bf16* f = fb + (size_t)j * 256 + lane * 4;
    float v = a0 * b2f(f[0]) + a1 * b2f(f[1]) + a2 * b2f(f[2]) + a3 * b2f(f[3]);
#pragma unroll
    for (int mk = 32; mk; mk >>= 1) v += __shfl_xor(v, mk);
    if (lane == 0) { float a = v + abv; s_att[j] = a > 0.f ? a : 0.01f * a; }
  }
  __syncthreads();
  float x = s_att[tid];
  float mx = x;
#pragma unroll
  for (int mk = 32; mk; mk >>= 1) mx = fmaxf(mx, __shfl_xor(mx, mk));
  if (lane == 0) s_red[w] = mx;
  __syncthreads();
  mx = fmaxf(fmaxf(s_red[0], s_red[1]), fmaxf(s_red[2], s_red[3]));
  float e = expf(x - mx);
  float sm = e;
#pragma unroll
  for (int mk = 32; mk; mk >>= 1) sm += __shfl_xor(sm, mk);
  if (lane == 0) s_red[4 + w] = sm;
  __syncthreads();
  sm = s_red[4] + s_red[5] + s_red[6] + s_red[7];
  __syncthreads();
  s_att[tid] = e / sm;
  __syncthreads();
  float acc = 0.f;
  for (int j = 0; j < 256; ++j) acc += s_att[j] * b2f(fb[(size_t)j * 256 + tid]);
  if (F32OUT) ndf[(size_t)i * 256 + tid] = acc;
  else        ndb[(size_t)i * 256 + tid] = f2b(acc);
}

// ---------------------------------------------------------------------------
extern "C" void kernel_launch(void* const* d_in, const int* in_sizes, int n_in,
                              void* d_out, int out_size, void* d_ws, size_t ws_size,
                              hipStream_t stream) {
  const float* edge_feats = (const float*)d_in[0];
  const float* node_feats = (const float*)d_in[1];
  const float* adapter_w  = (const float*)d_in[2];
  const float* adapter_b  = (const float*)d_in[3];
  const float* conv0_w    = (const float*)d_in[4];
  const float* conv0_b    = (const float*)d_in[5];
  const float* conv1_w    = (const float*)d_in[6];
  const float* conv1_b    = (const float*)d_in[7];
  const float* last_w     = (const float*)d_in[8];
  const float* last_b     = (const float*)d_in[9];
  const float* att_w      = (const float*)d_in[10];
  const float* att_b      = (const float*)d_in[11];
  float* out = (float*)d_out;

  char* ws = (char*)d_ws;
  size_t off = 0;
  bf16* Q   = (bf16*)(ws + off); off += (size_t)256 * 256 * 256 * 2;      // 33,554,432
  bf16* WP0 = (bf16*)(ws + off); off += (size_t)9 * 65536 * 2;
  bf16* WP1 = (bf16*)(ws + off); off += (size_t)9 * 65536 * 2;
  bf16* WP2 = (bf16*)(ws + off); off += (size_t)9 * 65536 * 2;
  bf16* WNP = (bf16*)(ws + off); off += (size_t)18 * 65536 * 2;           //  2,359,296
  float* TT = (float*)(ws + off); off += (size_t)2 * 3 * 65536 * 4;       //  1,572,864
  bf16* ND  = (bf16*)(ws + off); off += (size_t)65536 * 2;                //    131,072
  bf16* ZB  = (bf16*)(ws + off); off += 256;                              // known-safe total 41,156,864
  if (ws_size < off) {
    fill_sentinel<<<(out_size + 255) / 256, 256, 0, stream>>>(out, out_size);
    return;
  }

  zero_zb<<<1, 64, 0, stream>>>(ZB);
  pack_w<<<11520, 256, 0, stream>>>(conv0_w, conv1_w, last_w, WP0, WP1, WP2, WNP);

  for (int b = 0; b < 2; ++b) {
    // P: bf16 scratch inside the (f32) edge-out region of batch b
    bf16* P = (bf16*)(out + 131072 + (size_t)b * 16777216);
    float* edge_out = out + 131072 + (size_t)b * 16777216;
    float* node_out = out + (size_t)b * 65536;
    const float* eb = edge_feats + (size_t)b * 458752;
    const float* nb = node_feats + (size_t)b * 65536;

    adapter_k<<<256, 256, 0, stream>>>(eb, adapter_w, adapter_b, P);                 // E  @ P
    // block 1
    node_terms<float><<<384, 256, 0, stream>>>(nb, WNP, TT);
    conv3x3_k<1, 0><<<256, 512, 0, stream>>>(P, WP0, conv0_b, Q, TT, ZB);            // A  @ Q
    conv3x3_k<0, 0><<<256, 512, 0, stream>>>(Q, WP1, conv1_b, P, nullptr, ZB);       // B  @ P
    att_wsum<0><<<256, 256, 0, stream>>>(P, att_w, att_b, ND, nullptr);              // nd1 @ ND
    conv3x3_k<0, 0><<<256, 512, 0, stream>>>(P, WP2, last_b, Q, nullptr, ZB);        // C  @ Q
    // block 2
    node_terms<bf16><<<384, 256, 0, stream>>>(ND, WNP, TT);
    conv3x3_k<1, 0><<<256, 512, 0, stream>>>(Q, WP0, conv0_b, P, TT, ZB);            // D  @ P
    conv3x3_k<0, 0><<<256, 512, 0, stream>>>(P, WP1, conv1_b, Q, nullptr, ZB);       // E2 @ Q
    att_wsum<1><<<256, 256, 0, stream>>>(Q, att_w, att_b, nullptr, node_out);        // node out (f32)
    conv3x3_k<0, 1><<<256, 512, 0, stream>>>(Q, WP2, last_b, edge_out, nullptr, ZB); // edge out (f32)
  }
}